// Round 10
// baseline (474.077 us; speedup 1.0000x reference)
//
#include <hip/hip_runtime.h>
#include <hip/hip_bf16.h>

#define B_    16
#define O_    80
#define R_    512
#define INCH  4096
#define NCLS  151
#define EMB_  768
#define HID_  512
#define POOL_ 2048
#define GEO_  128

typedef unsigned short u16;
typedef __attribute__((ext_vector_type(4))) float  f32x4;
typedef __attribute__((ext_vector_type(8))) __bf16 bf16x8;

typedef const __attribute__((address_space(1))) void* as1_t;
typedef __attribute__((address_space(3))) void*       as3_t;
#define GLOAD16(g, l) __builtin_amdgcn_global_load_lds((as1_t)(g), (as3_t)(l), 16, 0, 0)

__device__ __forceinline__ u16 f2b(float f) {
    unsigned u = __float_as_uint(f);
    u += 0x7FFFu + ((u >> 16) & 1u);        // RNE
    return (u16)(u >> 16);
}
__device__ __forceinline__ float b2f(u16 b) {
    return __uint_as_float(((unsigned)b) << 16);
}

// ===========================================================================
// 256x256-tile bf16 GEMM, BK=64, 512 thr (8 waves 2Mx4N), LDS 2x64KB.
// R5 schedule (verbatim, 171us/988TF proven): register-level fragment
// double-buffer; 2 barriers + 1 vmcnt per K-tile. Swizzled LDS, 0 conflicts.
// PAIRMUL epilogue: out = bf16( relu(acc+bias2) * gather(fusB) ).
// SPLITK mode: grid = nbmn*S blocks; z=wg/nbmn selects K-slice (nt1 tiles at
// offset z*nt1*64); epilogue writes bf16 partials to Pb + z*mns, no bias.
// ===========================================================================
template<int MIDRELU, int ENDRELU, int PAIRMUL, int SPLITK>
__global__ __launch_bounds__(512, 2)
void gemm256(const u16* __restrict__ A1i, int lda1, const u16* __restrict__ B1i,
             int ldb1, int nt1,
             const u16* __restrict__ A2i, int lda2, const u16* __restrict__ B2i,
             int ldb2, int nt2,
             const float* __restrict__ bias1, const float* __restrict__ bias2,
             float* __restrict__ C, int ldc, int NBN,
             const int* __restrict__ ridx, const u16* __restrict__ fusB,
             int nbmn, size_t mns)
{
    __shared__ u16 lds[2][32768];           // 2 x (A 16384 + B 16384) elems

    const int tid = threadIdx.x;
    const int w = tid >> 6, l = tid & 63;
    const int wm = w >> 2, wn = w & 3;
    const int NT = nt1 + nt2;               // K-tiles of 64

    const int nwg = gridDim.x;
    const int cpx = nwg >> 3;
    const int wg  = (blockIdx.x & 7) * cpx + (blockIdx.x >> 3);
    int mb, nb, z = 0;
    if (SPLITK) { z = wg / nbmn; const int r2 = wg % nbmn; mb = r2 / NBN; nb = r2 % NBN; }
    else        { mb = wg / NBN; nb = wg % NBN; }
    const int m0 = mb * 256, n0 = nb * 256;
    const int kb = SPLITK ? z * nt1 * 64 : 0;

    const int slA  = (tid & 7) ^ ((tid >> 3) & 7);
    const int mloc = ((slA >> 2) << 7) + (tid >> 3);
    const int kloc = (slA & 3) << 3;
    const int wo   = w << 9;

    auto stage = [&](int st, int reg8, u16* buf) {
        if (st >= NT) return;
        const int isA = (reg8 < 4) ? 1 : 0;
        const int ks  = (reg8 >> 1) & 1, sub = reg8 & 1;
        const u16* base; int ld, stl;
        if (st < nt1) { base = isA ? A1i : B1i; ld = isA ? lda1 : ldb1; stl = st; }
        else          { base = isA ? A2i : B2i; ld = isA ? lda2 : ldb2; stl = st - nt1; }
        const int x0 = isA ? m0 : n0;
        const u16* src = base + (size_t)(x0 + mloc + (sub << 6)) * ld
                       + kb + stl * 64 + ks * 32 + kloc;
        u16* dst = buf + (isA ? 0 : 16384) + (ks << 13) + (sub << 12) + wo;
        GLOAD16(src, dst);
    };

    const int lr = l & 15, kq = l >> 4, lr7 = l & 7;
    const int aob = lr * 64 + (((wm << 2) | kq) ^ lr7) * 8;
    const int bob = 16384 + ((wn & 1) << 12) + lr * 64
                  + ((((wn >> 1) << 2) | kq) ^ lr7) * 8;

    f32x4 acc[8][4] = {};
    bf16x8 avA[4], avB[4], bvA[4], bvB[4];

    u16* const b0 = &lds[0][0];
    u16* const b1 = &lds[1][0];

    // ---- prologue: stage tiles 0 and 1 fully; land tile 0; pre-read X0 frags
#pragma unroll
    for (int r8 = 0; r8 < 8; ++r8) stage(0, r8, b0);
#pragma unroll
    for (int r8 = 0; r8 < 8; ++r8) stage(1, r8, b1);
    asm volatile("s_waitcnt vmcnt(8)" ::: "memory");
    asm volatile("s_barrier" ::: "memory");
#pragma unroll
    for (int f = 0; f < 4; ++f) avA[f] = *(const bf16x8*)(b0 + aob + f * 1024);
#pragma unroll
    for (int j = 0; j < 4; ++j) bvA[j] = *(const bf16x8*)(b0 + bob + j * 1024);

    for (int u = 0; u < NT; ++u) {
        u16* const bufc = (u & 1) ? b1 : b0;
        u16* const bufn = (u & 1) ? b0 : b1;

        // ======== X0: MFMA(ks0,mq0); read avB<-A(ks0,mq1); stage r0,r4,r5 ====
        asm volatile("s_barrier" ::: "memory");          // alpha
#pragma unroll
        for (int f = 0; f < 4; ++f)
            avB[f] = *(const bf16x8*)(bufc + 4096 + aob + f * 1024);
        stage(u + 2, 0, bufc); stage(u + 2, 4, bufc); stage(u + 2, 5, bufc);
        __builtin_amdgcn_s_setprio(1);
#pragma unroll
        for (int f = 0; f < 4; ++f)
#pragma unroll
            for (int j = 0; j < 4; ++j)
                acc[f][j] = __builtin_amdgcn_mfma_f32_16x16x32_bf16(
                    avA[f], bvA[j], acc[f][j], 0, 0, 0);
        __builtin_amdgcn_s_setprio(0);

        // ======== X1: MFMA(ks0,mq1); read avA<-A(ks1,mq0), bvB<-B(ks1) ======
#pragma unroll
        for (int f = 0; f < 4; ++f)
            avA[f] = *(const bf16x8*)(bufc + 8192 + aob + f * 1024);
#pragma unroll
        for (int j = 0; j < 4; ++j)
            bvB[j] = *(const bf16x8*)(bufc + 8192 + bob + j * 1024);
        __builtin_amdgcn_s_setprio(1);
#pragma unroll
        for (int f = 0; f < 4; ++f)
#pragma unroll
            for (int j = 0; j < 4; ++j)
                acc[4 + f][j] = __builtin_amdgcn_mfma_f32_16x16x32_bf16(
                    avB[f], bvA[j], acc[4 + f][j], 0, 0, 0);
        __builtin_amdgcn_s_setprio(0);

        // ======== X2: MFMA(ks1,mq0); read avB<-A(ks1,mq1); stage r1,r2,r6,r7
#pragma unroll
        for (int f = 0; f < 4; ++f)
            avB[f] = *(const bf16x8*)(bufc + 8192 + 4096 + aob + f * 1024);
        stage(u + 2, 1, bufc); stage(u + 2, 2, bufc);
        stage(u + 2, 6, bufc); stage(u + 2, 7, bufc);
        __builtin_amdgcn_s_setprio(1);
#pragma unroll
        for (int f = 0; f < 4; ++f)
#pragma unroll
            for (int j = 0; j < 4; ++j)
                acc[f][j] = __builtin_amdgcn_mfma_f32_16x16x32_bf16(
                    avA[f], bvB[j], acc[f][j], 0, 0, 0);
        __builtin_amdgcn_s_setprio(0);

        // ======== X3: vmcnt+beta; MFMA(ks1,mq1); pre-read next tile; stage r3
        if (u + 2 < NT) asm volatile("s_waitcnt vmcnt(7)" ::: "memory");
        else            asm volatile("s_waitcnt vmcnt(0)" ::: "memory");
        asm volatile("s_barrier" ::: "memory");          // beta: bufn ready
        if (u + 1 < NT) {
#pragma unroll
            for (int f = 0; f < 4; ++f)
                avA[f] = *(const bf16x8*)(bufn + aob + f * 1024);
#pragma unroll
            for (int j = 0; j < 4; ++j)
                bvA[j] = *(const bf16x8*)(bufn + bob + j * 1024);
        }
        stage(u + 2, 3, bufc);
        __builtin_amdgcn_s_setprio(1);
#pragma unroll
        for (int f = 0; f < 4; ++f)
#pragma unroll
            for (int j = 0; j < 4; ++j)
                acc[4 + f][j] = __builtin_amdgcn_mfma_f32_16x16x32_bf16(
                    avB[f], bvB[j], acc[4 + f][j], 0, 0, 0);
        __builtin_amdgcn_s_setprio(0);

        if (MIDRELU && u == nt1 - 1) {
#pragma unroll
            for (int j = 0; j < 4; ++j) {
                const float bb = bias1[n0 + wn * 64 + j * 16 + lr];
#pragma unroll
                for (int i = 0; i < 8; ++i)
#pragma unroll
                    for (int r = 0; r < 4; ++r)
                        acc[i][j][r] = fmaxf(acc[i][j][r] + bb, 0.f);
            }
        }
    }

    // ---- epilogue (C/D layout: col=lane&15, row=(lane>>4)*4+reg) ----
    const int cb = n0 + wn * 64 + lr;
    const int rb = m0 + wm * 128 + kq * 4;
#pragma unroll
    for (int j = 0; j < 4; ++j) {
        const int col = cb + j * 16;
        const float bv2 = SPLITK ? 0.f : bias2[col];
#pragma unroll
        for (int i = 0; i < 8; ++i)
#pragma unroll
            for (int r = 0; r < 4; ++r) {
                const int prow = rb + i * 16 + r;
                if (SPLITK) {
                    ((u16*)C)[z * mns + (size_t)prow * ldc + col] = f2b(acc[i][j][r]);
                    continue;
                }
                float v = acc[i][j][r] + bv2;
                if (ENDRELU) v = fmaxf(v, 0.f);
                if (PAIRMUL) {
                    const int ii = ridx[prow * 2 + (col >> 9)];
                    const float g = b2f(fusB[(size_t)((prow >> 9) * O_ + ii) * 1024 + col]);
                    ((u16*)C)[(size_t)prow * ldc + col] = f2b(v * g);
                } else {
                    C[(size_t)prow * ldc + col] = v;
                }
            }
    }
}

// ---------------------------------------------------------------------------
// Split-K bf16 MFMA GEMM (objhid): P[z][M,N] = A*Bt^T over K-slice, f32 out.
// ---------------------------------------------------------------------------
__global__ __launch_bounds__(256, 2)
void gemm_splitk(const u16* __restrict__ A, const u16* __restrict__ Bt,
                 float* __restrict__ P, int K, int KS, int N, int MN)
{
    __shared__ u16 sA[128 * 32];
    __shared__ u16 sB[128 * 32];
    const int tid = threadIdx.x;
    const int w = tid >> 6, l = tid & 63;
    const int m0 = blockIdx.y * 128, n0 = blockIdx.x * 128;
    const int wr = (w >> 1) * 64, wc = (w & 1) * 64;

    const int e0 = w * 512 + l * 8;
    const int r0 = e0 >> 5, c0 = e0 & 31;
    const int r1 = r0 + 64;

    const u16* gA0 = A + (size_t)(m0 + r0) * K + c0;
    const u16* gA1 = A + (size_t)(m0 + r1) * K + c0;
    const u16* gB0 = Bt + (size_t)(n0 + r0) * K + c0;
    const u16* gB1 = Bt + (size_t)(n0 + r1) * K + c0;
    u16* lA0 = sA + w * 512;
    u16* lA1 = sA + 2048 + w * 512;
    u16* lB0 = sB + w * 512;
    u16* lB1 = sB + 2048 + w * 512;

    f32x4 acc[4][4] = {};
    const int lr = l & 15, lk = (l >> 4) * 8;
    const int kbeg = blockIdx.z * KS, kend = kbeg + KS;

    for (int k0 = kbeg; k0 < kend; k0 += 32) {
        __syncthreads();
        GLOAD16(gA0 + k0, lA0);
        GLOAD16(gA1 + k0, lA1);
        GLOAD16(gB0 + k0, lB0);
        GLOAD16(gB1 + k0, lB1);
        __syncthreads();

        bf16x8 av[4], bv[4];
#pragma unroll
        for (int f = 0; f < 4; ++f) {
            av[f] = *(const bf16x8*)&sA[(wr + f * 16 + lr) * 32 + lk];
            bv[f] = *(const bf16x8*)&sB[(wc + f * 16 + lr) * 32 + lk];
        }
#pragma unroll
        for (int i = 0; i < 4; ++i)
#pragma unroll
            for (int j = 0; j < 4; ++j)
                acc[i][j] = __builtin_amdgcn_mfma_f32_16x16x32_bf16(
                    av[i], bv[j], acc[i][j], 0, 0, 0);
    }

    float* out = P + (size_t)blockIdx.z * MN;
    const int cb = n0 + wc + lr;
    const int rb = m0 + wr + (l >> 4) * 4;
#pragma unroll
    for (int j = 0; j < 4; ++j) {
        const int c = cb + j * 16;
#pragma unroll
        for (int i = 0; i < 4; ++i)
#pragma unroll
            for (int r = 0; r < 4; ++r)
                out[(size_t)(rb + i * 16 + r) * N + c] = acc[i][j][r];
    }
}

// reduce NS f32 split-K partials + bias (+relu)
template<int NS, int RELU, int OUTB>
__global__ void k_redux(const float* __restrict__ P, int ldP, int colbase,
                        int logW, size_t MN, const float* __restrict__ bias,
                        void* __restrict__ dst, int ldc)
{
    const int i4 = (blockIdx.x * 256 + threadIdx.x) * 4;
    const int row = i4 >> logW, col = i4 & ((1 << logW) - 1);
    const float* src = P + (size_t)row * ldP + colbase + col;
    float4 s = *(const float4*)src;
#pragma unroll
    for (int z = 1; z < NS; ++z) {
        const float4 v = *(const float4*)(src + (size_t)z * MN);
        s.x += v.x; s.y += v.y; s.z += v.z; s.w += v.w;
    }
    const float4 bb = *(const float4*)(bias + col);
    s.x += bb.x; s.y += bb.y; s.z += bb.z; s.w += bb.w;
    if (RELU) {
        s.x = fmaxf(s.x, 0.f); s.y = fmaxf(s.y, 0.f);
        s.z = fmaxf(s.z, 0.f); s.w = fmaxf(s.w, 0.f);
    }
    if (OUTB) {
        ushort4 o;
        o.x = f2b(s.x); o.y = f2b(s.y); o.z = f2b(s.z); o.w = f2b(s.w);
        *(ushort4*)((u16*)dst + (size_t)row * ldc + col) = o;
    } else {
        *(float4*)((float*)dst + (size_t)row * ldc + col) = s;
    }
}

// fused UA reduce: NS bf16 partials over [1280 x 3072]; cols<1024 -> fusedB
// (bf16, +updim_b); cols>=1024 -> outAug (f32, +augb, relu).
template<int NS>
__global__ void k_reduxUA(const u16* __restrict__ P, size_t MN,
                          const float* __restrict__ b1, const float* __restrict__ b2,
                          u16* __restrict__ fusedB, float* __restrict__ outAug)
{
    const int i4 = (blockIdx.x * 256 + threadIdx.x) * 4;
    const int row = i4 / 3072, col = i4 - row * 3072;
    const u16* src = P + (size_t)row * 3072 + col;
    float s[4] = {};
#pragma unroll
    for (int z = 0; z < NS; ++z) {
        const ushort4 v = *(const ushort4*)(src + (size_t)z * MN);
        s[0] += b2f(v.x); s[1] += b2f(v.y); s[2] += b2f(v.z); s[3] += b2f(v.w);
    }
    if (col < 1024) {
        const float4 bb = *(const float4*)(b1 + col);
        ushort4 o;
        o.x = f2b(s[0] + bb.x); o.y = f2b(s[1] + bb.y);
        o.z = f2b(s[2] + bb.z); o.w = f2b(s[3] + bb.w);
        *(ushort4*)(fusedB + (size_t)row * 1024 + col) = o;
    } else {
        const int c2 = col - 1024;
        const float4 bb = *(const float4*)(b2 + c2);
        float4 o;
        o.x = fmaxf(s[0] + bb.x, 0.f); o.y = fmaxf(s[1] + bb.y, 0.f);
        o.z = fmaxf(s[2] + bb.z, 0.f); o.w = fmaxf(s[3] + bb.w, 0.f);
        *(float4*)(outAug + (size_t)row * 2048 + c2) = o;
    }
}

// ---------------------------------------------------------------------------
// batched transpose + f32->bf16 for all 6 weights in ONE launch.
// ---------------------------------------------------------------------------
struct TDescs {
    const float* W[6]; u16* T[6];
    int K[6], N[6], nbx[6];
    int base[7];
};

__global__ void k_transpose_all(TDescs d)
{
    __shared__ float tile[64][65];
    const int b = blockIdx.x;
    int i = 0;
    while (b >= d.base[i + 1]) ++i;
    const int loc = b - d.base[i];
    const int nbx = d.nbx[i];
    const int bx = loc % nbx, by = loc / nbx;
    const int K = d.K[i], N = d.N[i];
    const float* W = d.W[i];
    u16* Wt = d.T[i];
    const int k0 = by * 64, n0 = bx * 64;
    const int tr = threadIdx.x >> 6, tc = threadIdx.x & 63;
    for (int rr = tr; rr < 64; rr += 4)
        tile[rr][tc] = W[(size_t)(k0 + rr) * N + n0 + tc];
    __syncthreads();
    for (int rr = tr; rr < 64; rr += 4)
        Wt[(size_t)(n0 + rr) * K + k0 + tc] = f2b(tile[tc][rr]);
}

// f32 -> bf16 elementwise (n multiple of 4)
__global__ void k_f2b4(const float4* __restrict__ in, ushort4* __restrict__ out,
                       int n4)
{
    int i = blockIdx.x * 256 + threadIdx.x;
    const int stride = gridDim.x * 256;
    for (; i < n4; i += stride) {
        float4 v = in[i];
        ushort4 o;
        o.x = f2b(v.x); o.y = f2b(v.y); o.z = f2b(v.z); o.w = f2b(v.w);
        out[i] = o;
    }
}

// fused per-row prep: pack(roi->cat1,aaug; embl->aaug) + softmax@embd + posMLP
__global__ __launch_bounds__(256, 4)
void k_prep(const float* __restrict__ roi, const float* __restrict__ embl,
            const int* __restrict__ labels, const float* __restrict__ logits,
            const float* __restrict__ embd, const float* __restrict__ pos9,
            const float* __restrict__ w1, const float* __restrict__ b1,
            const float* __restrict__ g, const float* __restrict__ bb,
            const float* __restrict__ mu, const float* __restrict__ var,
            const float* __restrict__ w2, const float* __restrict__ b2,
            u16* __restrict__ cat1, u16* __restrict__ aaug)
{
    const int i = blockIdx.x, t = threadIdx.x;   // 256
    __shared__ float red[256];
    __shared__ float pr[NCLS];
    __shared__ float pi[9];
    __shared__ float h[32];
    u16* c1 = cat1 + (size_t)i * 4992;
    u16* aa = aaug + (size_t)i * 5376;

    // ---- softmax(logits[i]) -> pr ----
    float v = (t < NCLS) ? logits[i * NCLS + t] : -3.4e38f;
    red[t] = v; __syncthreads();
    for (int s = 128; s > 0; s >>= 1) {
        if (t < s) red[t] = fmaxf(red[t], red[t + s]);
        __syncthreads();
    }
    const float mx = red[0]; __syncthreads();
    float e = (t < NCLS) ? expf(v - mx) : 0.f;
    red[t] = e; __syncthreads();
    for (int s = 128; s > 0; s >>= 1) {
        if (t < s) red[t] += red[t + s];
        __syncthreads();
    }
    const float inv = 1.f / red[0];
    if (t < NCLS) pr[t] = e * inv;
    // ---- pos fc1 + BN (threads 0-31) ----
    if (t < 9) pi[t] = pos9[i * 9 + t];
    __syncthreads();
    if (t < 32) {
        float s = b1[t];
        for (int k = 0; k < 9; ++k) s += pi[k] * w1[k * 32 + t];
        h[t] = (s - mu[t]) * rsqrtf(var[t] + 1e-5f) * g[t] + bb[t];
    }
    __syncthreads();

    // ---- pack roi + emb_label ----
    const float* r = roi + (size_t)i * INCH;
    for (int c = t; c < INCH; c += 256) {
        u16 bv = f2b(r[c]);
        c1[c] = bv;
        aa[EMB_ + c] = bv;
    }
    const float* el = embl + (size_t)labels[i] * EMB_;
    for (int c = t; c < EMB_; c += 256) aa[c] = f2b(el[c]);

    // ---- pr @ embd -> cat1[4096:4864] ----
    for (int j = t; j < EMB_; j += 256) {
        float s = 0.f;
        for (int k = 0; k < NCLS; ++k) s += pr[k] * embd[k * EMB_ + j];
        c1[INCH + j] = f2b(s);
    }
    // ---- pos fc2 + relu -> cat1[4864:4992] ----
    if (t < GEO_) {
        float s = b2[t];
        for (int k = 0; k < 32; ++k) s += h[k] * w2[k * GEO_ + t];
        c1[INCH + EMB_ + t] = f2b(fmaxf(s, 0.f));
    }
}

// geo(32) + spt1 (K=32) + relu, 16 pairs/block, w1 staged in LDS.
__global__ __launch_bounds__(256, 2)
void k_geo_spt1(const float* __restrict__ boxes, const int* __restrict__ ridx,
                const float* __restrict__ w1, const float* __restrict__ b1,
                u16* __restrict__ out)
{
    __shared__ float w1s[32][512];
    __shared__ float geos[16][32];
    const int t = threadIdx.x;       // 256
    const int p0 = blockIdx.x * 16;
    for (int i = t; i < 32 * 512; i += 256)
        w1s[i >> 9][i & 511] = w1[i];
    if (t < 16) {
        const int p = p0 + t;
        const int b = p >> 9;
        const int i0 = ridx[p * 2 + 0];
        const int i1 = ridx[p * 2 + 1];
        const float* x = boxes + (size_t)(b * O_ + i0) * 4;
        const float* y = boxes + (size_t)(b * O_ + i1) * 4;
        float a0 = x[0], a1 = x[1], a2 = x[2], a3 = x[3];
        float c0 = y[0], c1 = y[1], c2 = y[2], c3 = y[3];
        float* g = geos[t];
        g[0] = a0; g[1] = a1; g[2] = a2; g[3] = a3;
        g[4] = (a0 + a2) * 0.5f; g[5] = (a1 + a3) * 0.5f;
        g[6] = a2 - a0; g[7] = a3 - a1;
        g[8] = c0; g[9] = c1; g[10] = c2; g[11] = c3;
        g[12] = (c0 + c2) * 0.5f; g[13] = (c1 + c3) * 0.5f;
        g[14] = c2 - c0; g[15] = c3 - c1;
        float u0 = fminf(a0, c0), u1 = fminf(a1, c1);
        float u2 = fmaxf(a2, c2), u3 = fmaxf(a3, c3);
        g[16] = u0; g[17] = u1; g[18] = u2; g[19] = u3;
        g[20] = (u0 + u2) * 0.5f; g[21] = (u1 + u3) * 0.5f;
        g[22] = u2 - u0; g[23] = u3 - u1;
        float q0 = fmaxf(a0, c0), q1 = fmaxf(a1, c1);
        float q2 = fminf(a2, c2), q3 = fminf(a3, c3);
        if (q0 <= q2 && q1 <= q3) {
            g[24] = q0; g[25] = q1; g[26] = q2; g[27] = q3;
            g[28] = (q0 + q2) * 0.5f; g[29] = (q1 + q3) * 0.5f;
            g[30] = q2 - q0; g[31] = q3 - q1;
        } else {
            for (int k = 24; k < 32; ++k) g[k] = 0.f;
        }
    }
    __syncthreads();
    for (int e = t; e < 16 * 512; e += 256) {
        const int p = e >> 9, j = e & 511;
        float s = b1[j];
#pragma unroll
        for (int k = 0; k < 32; ++k) s += geos[p][k] * w1s[k][j];
        out[(size_t)(p0 + p) * HID_ + j] = f2b(fmaxf(s, 0.f));
    }
}

// ---------------------------------------------------------------------------
extern "C" void kernel_launch(void* const* d_in, const int* in_sizes, int n_in,
                              void* d_out, int out_size, void* d_ws, size_t ws_size,
                              hipStream_t stream)
{
    (void)in_sizes; (void)n_in; (void)out_size; (void)ws_size;
    const float* roi     = (const float*)d_in[0];
    const float* unionf  = (const float*)d_in[1];
    const float* logits  = (const float*)d_in[2];
    const float* pos9    = (const float*)d_in[3];
    const float* boxes   = (const float*)d_in[4];
    const int*   labels  = (const int*)d_in[5];
    const int*   relidx  = (const int*)d_in[6];
    const float* embd    = (const float*)d_in[7];
    const float* embl    = (const float*)d_in[8];
    const float* relup_w = (const float*)d_in[9];
    const float* relup_b = (const float*)d_in[10];
    const float* updim_w = (const float*)d_in[11];
    const float* updim_b = (const float*)d_in[12];
    const float* fc1w    = (const float*)d_in[13];
    const float* fc1b    = (const float*)d_in[14];
    const float* bng     = (const float*)d_in[15];
    const float* bnb     = (const float*)d_in[16];
    const float* bnm     = (const float*)d_in[17];
    const float* bnv     = (const float*)d_in[18];
    const float* fc2w    = (const float*)d_in[19];
    const float* fc2b    = (const float*)d_in[20];
    const float* spt1w   = (const float*)d_in[21];
    const float* spt1b   = (const float*)d_in[22];
    const float* spt2w   = (const float*)d_in[23];
    const float* spt2b   = (const float*)d_in[24];
    const float* finw    = (const float*)d_in[25];
    const float* finb    = (const float*)d_in[26];
    const float* objhw   = (const float*)d_in[27];
    const float* objhb   = (const float*)d_in[28];
    const float* augw    = (const float*)d_in[29];
    const float* augb    = (const float*)d_in[30];

    char* wp = (char*)d_ws;
    auto take = [&](size_t bytes) {
        char* r = wp; wp += (bytes + 255) & ~(size_t)255; return r;
    };
    u16* wtObj   = (u16*)take((size_t)512  * 4992 * 2);
    u16* wtUA    = (u16*)take((size_t)3072 * 5376 * 2);   // updim rows 0-1023, aug 1024-3071
    u16* wtSpt2  = (u16*)take((size_t)1024 * 512  * 2);
    u16* wtFin   = (u16*)take((size_t)2048 * 1024 * 2);
    u16* wtRelup = (u16*)take((size_t)2048 * 4096 * 2);
    u16* aCat1   = (u16*)take((size_t)1280 * 4992 * 2);
    u16* aAug    = (u16*)take((size_t)1280 * 5376 * 2);
    u16* aUnion  = (u16*)take((size_t)8192 * 4096 * 2);
    u16* aSpt1   = (u16*)take((size_t)8192 * 512  * 2);
    u16* fusedB  = (u16*)take((size_t)1280 * 1024 * 2);
    u16* aPair   = (u16*)take((size_t)8192 * 1024 * 2);
    float* Pscr  = (float*)take((size_t)8192 * 1024 * 4); // scratch after aPair
    (void)Pscr;
    // partial buffer aliases (aPair + Pscr) = 50.3MB:
    //   objhid: 6 x 1280x512 f32   = 15.7MB
    //   UA:     6 x 1280x3072 bf16 = 47.2MB
    // both dead before spt2's PAIRMUL epilogue writes aPair.
    float* Pbuf  = (float*)aPair;
    u16*   PbufB = (u16*)aPair;

    float* outAug = (float*)d_out;                          // [1280,2048]
    float* outRel = (float*)d_out + (size_t)1280 * 2048;    // [8192,2048]

    // all 6 weight transposes in one launch
    TDescs td;
    td.W[0] = objhw;   td.T[0] = wtObj;                      td.K[0] = 4992; td.N[0] = 512;
    td.W[1] = updim_w; td.T[1] = wtUA;                       td.K[1] = 5376; td.N[1] = 1024;
    td.W[2] = augw;    td.T[2] = wtUA + (size_t)1024 * 5376; td.K[2] = 5376; td.N[2] = 2048;
    td.W[3] = spt2w;   td.T[3] = wtSpt2;                     td.K[3] = 512;  td.N[3] = 1024;
    td.W[4] = finw;    td.T[4] = wtFin;                      td.K[4] = 1024; td.N[4] = 2048;
    td.W[5] = relup_w; td.T[5] = wtRelup;                    td.K[5] = 4096; td.N[5] = 2048;
    int tb = 0;
    for (int i = 0; i < 6; ++i) {
        td.nbx[i] = td.N[i] / 64;
        td.base[i] = tb;
        tb += (td.N[i] / 64) * (td.K[i] / 64);
    }
    td.base[6] = tb;   // 7344
    k_transpose_all<<<tb, 256, 0, stream>>>(td);

    // activations prep
    k_f2b4<<<2048, 256, 0, stream>>>((const float4*)unionf, (ushort4*)aUnion,
                                     (8192 * 4096) / 4);
    k_prep<<<1280, 256, 0, stream>>>(roi, embl, labels, logits, embd, pos9,
                                     fc1w, fc1b, bng, bnb, bnm, bnv, fc2w, fc2b,
                                     aCat1, aAug);
    k_geo_spt1<<<512, 256, 0, stream>>>(boxes, relidx, spt1w, spt1b, aSpt1);

    // aug_hid = cat1 @ objhid  (split-K 6 f32 -> bf16 cols of aAug)
    gemm_splitk<<<dim3(4, 10, 6), 256, 0, stream>>>(aCat1, wtObj, Pbuf, 4992, 832,
                                                    512, 1280 * 512);
    k_redux<6, 0, 1><<<640, 256, 0, stream>>>(Pbuf, 512, 0, 9, (size_t)1280 * 512,
                                              objhb, (void*)(aAug + 4864), 5376);

    // [fused | augment_pre] = aAug @ [updim | aug]  via gemm256 split-K
    // (S=6, grid 60x6=360, K-slice 896 = 14 tiles of 64, bf16 partials)
    gemm256<0, 0, 0, 1><<<dim3(360), 512, 0, stream>>>(
        aAug, 5376, wtUA, 5376, 14,
        aAug, 5376, wtUA, 5376, 0,
        updim_b, updim_b, (float*)PbufB, 3072, 12, nullptr, nullptr,
        60, (size_t)1280 * 3072);
    k_reduxUA<6><<<3840, 256, 0, stream>>>(PbufB, (size_t)1280 * 3072,
                                           updim_b, augb, fusedB, outAug);

    // spt = relu(spt1out @ spt2 + b); epilogue: aPair = bf16(spt * gather(fused))
    gemm256<0, 1, 1, 0><<<dim3(128), 512, 0, stream>>>(
        aSpt1, 512, wtSpt2, 512, 8,
        aSpt1, 512, wtSpt2, 512, 0,
        spt2b, spt2b, (float*)aPair, 1024, 4, relidx, fusedB, 0, 0);

    // rel_features = relu(pair@fin + finb) + union@relup + relup_b  (fused)
    gemm256<1, 0, 0, 0><<<dim3(256), 512, 0, stream>>>(
        aPair, 1024, wtFin, 1024, 16,
        aUnion, 4096, wtRelup, 4096, 64,
        finb, relup_b, outRel, 2048, 8, nullptr, nullptr, 0, 0);
}

// Round 11
// 454.105 us; speedup vs baseline: 1.0440x; 1.0440x over previous
//
#include <hip/hip_runtime.h>
#include <hip/hip_bf16.h>

#define B_    16
#define O_    80
#define R_    512
#define INCH  4096
#define NCLS  151
#define EMB_  768
#define HID_  512
#define POOL_ 2048
#define GEO_  128

typedef unsigned short u16;
typedef __attribute__((ext_vector_type(4))) float  f32x4;
typedef __attribute__((ext_vector_type(8))) __bf16 bf16x8;

typedef const __attribute__((address_space(1))) void* as1_t;
typedef __attribute__((address_space(3))) void*       as3_t;
#define GLOAD16(g, l) __builtin_amdgcn_global_load_lds((as1_t)(g), (as3_t)(l), 16, 0, 0)

__device__ __forceinline__ u16 f2b(float f) {
    unsigned u = __float_as_uint(f);
    u += 0x7FFFu + ((u >> 16) & 1u);        // RNE
    return (u16)(u >> 16);
}
__device__ __forceinline__ float b2f(u16 b) {
    return __uint_as_float(((unsigned)b) << 16);
}

// ===========================================================================
// 256x256-tile bf16 GEMM, BK=64, 512 thr (8 waves 2Mx4N), LDS 2x64KB.
// R5 schedule (verbatim, 171us/988TF proven): register-level fragment
// double-buffer; 2 barriers + 1 vmcnt per K-tile. Swizzled LDS, 0 conflicts.
// PAIRMUL epilogue: out = bf16( relu(acc+bias2) * gather(fusB) ).
// SPLITK mode: grid = nbmn*S blocks; z=wg/nbmn selects K-slice (nt1 tiles at
// offset z*nt1*64); epilogue writes bf16 partials to Pb + z*mns, no bias.
// ===========================================================================
template<int MIDRELU, int ENDRELU, int PAIRMUL, int SPLITK>
__global__ __launch_bounds__(512, 2)
void gemm256(const u16* __restrict__ A1i, int lda1, const u16* __restrict__ B1i,
             int ldb1, int nt1,
             const u16* __restrict__ A2i, int lda2, const u16* __restrict__ B2i,
             int ldb2, int nt2,
             const float* __restrict__ bias1, const float* __restrict__ bias2,
             float* __restrict__ C, int ldc, int NBN,
             const int* __restrict__ ridx, const u16* __restrict__ fusB,
             int nbmn, size_t mns)
{
    __shared__ u16 lds[2][32768];           // 2 x (A 16384 + B 16384) elems

    const int tid = threadIdx.x;
    const int w = tid >> 6, l = tid & 63;
    const int wm = w >> 2, wn = w & 3;
    const int NT = nt1 + nt2;               // K-tiles of 64

    const int nwg = gridDim.x;
    const int cpx = nwg >> 3;
    const int wg  = (blockIdx.x & 7) * cpx + (blockIdx.x >> 3);
    int mb, nb, z = 0;
    if (SPLITK) { z = wg / nbmn; const int r2 = wg % nbmn; mb = r2 / NBN; nb = r2 % NBN; }
    else        { mb = wg / NBN; nb = wg % NBN; }
    const int m0 = mb * 256, n0 = nb * 256;
    const int kb = SPLITK ? z * nt1 * 64 : 0;

    const int slA  = (tid & 7) ^ ((tid >> 3) & 7);
    const int mloc = ((slA >> 2) << 7) + (tid >> 3);
    const int kloc = (slA & 3) << 3;
    const int wo   = w << 9;

    auto stage = [&](int st, int reg8, u16* buf) {
        if (st >= NT) return;
        const int isA = (reg8 < 4) ? 1 : 0;
        const int ks  = (reg8 >> 1) & 1, sub = reg8 & 1;
        const u16* base; int ld, stl;
        if (st < nt1) { base = isA ? A1i : B1i; ld = isA ? lda1 : ldb1; stl = st; }
        else          { base = isA ? A2i : B2i; ld = isA ? lda2 : ldb2; stl = st - nt1; }
        const int x0 = isA ? m0 : n0;
        const u16* src = base + (size_t)(x0 + mloc + (sub << 6)) * ld
                       + kb + stl * 64 + ks * 32 + kloc;
        u16* dst = buf + (isA ? 0 : 16384) + (ks << 13) + (sub << 12) + wo;
        GLOAD16(src, dst);
    };

    const int lr = l & 15, kq = l >> 4, lr7 = l & 7;
    const int aob = lr * 64 + (((wm << 2) | kq) ^ lr7) * 8;
    const int bob = 16384 + ((wn & 1) << 12) + lr * 64
                  + ((((wn >> 1) << 2) | kq) ^ lr7) * 8;

    f32x4 acc[8][4] = {};
    bf16x8 avA[4], avB[4], bvA[4], bvB[4];

    u16* const b0 = &lds[0][0];
    u16* const b1 = &lds[1][0];

    // ---- prologue: stage tiles 0 and 1 fully; land tile 0; pre-read X0 frags
#pragma unroll
    for (int r8 = 0; r8 < 8; ++r8) stage(0, r8, b0);
#pragma unroll
    for (int r8 = 0; r8 < 8; ++r8) stage(1, r8, b1);
    asm volatile("s_waitcnt vmcnt(8)" ::: "memory");
    asm volatile("s_barrier" ::: "memory");
#pragma unroll
    for (int f = 0; f < 4; ++f) avA[f] = *(const bf16x8*)(b0 + aob + f * 1024);
#pragma unroll
    for (int j = 0; j < 4; ++j) bvA[j] = *(const bf16x8*)(b0 + bob + j * 1024);

    for (int u = 0; u < NT; ++u) {
        u16* const bufc = (u & 1) ? b1 : b0;
        u16* const bufn = (u & 1) ? b0 : b1;

        // ======== X0: MFMA(ks0,mq0); read avB<-A(ks0,mq1); stage r0,r4,r5 ====
        asm volatile("s_barrier" ::: "memory");          // alpha
#pragma unroll
        for (int f = 0; f < 4; ++f)
            avB[f] = *(const bf16x8*)(bufc + 4096 + aob + f * 1024);
        stage(u + 2, 0, bufc); stage(u + 2, 4, bufc); stage(u + 2, 5, bufc);
        __builtin_amdgcn_s_setprio(1);
#pragma unroll
        for (int f = 0; f < 4; ++f)
#pragma unroll
            for (int j = 0; j < 4; ++j)
                acc[f][j] = __builtin_amdgcn_mfma_f32_16x16x32_bf16(
                    avA[f], bvA[j], acc[f][j], 0, 0, 0);
        __builtin_amdgcn_s_setprio(0);

        // ======== X1: MFMA(ks0,mq1); read avA<-A(ks1,mq0), bvB<-B(ks1) ======
#pragma unroll
        for (int f = 0; f < 4; ++f)
            avA[f] = *(const bf16x8*)(bufc + 8192 + aob + f * 1024);
#pragma unroll
        for (int j = 0; j < 4; ++j)
            bvB[j] = *(const bf16x8*)(bufc + 8192 + bob + j * 1024);
        __builtin_amdgcn_s_setprio(1);
#pragma unroll
        for (int f = 0; f < 4; ++f)
#pragma unroll
            for (int j = 0; j < 4; ++j)
                acc[4 + f][j] = __builtin_amdgcn_mfma_f32_16x16x32_bf16(
                    avB[f], bvA[j], acc[4 + f][j], 0, 0, 0);
        __builtin_amdgcn_s_setprio(0);

        // ======== X2: MFMA(ks1,mq0); read avB<-A(ks1,mq1); stage r1,r2,r6,r7
#pragma unroll
        for (int f = 0; f < 4; ++f)
            avB[f] = *(const bf16x8*)(bufc + 8192 + 4096 + aob + f * 1024);
        stage(u + 2, 1, bufc); stage(u + 2, 2, bufc);
        stage(u + 2, 6, bufc); stage(u + 2, 7, bufc);
        __builtin_amdgcn_s_setprio(1);
#pragma unroll
        for (int f = 0; f < 4; ++f)
#pragma unroll
            for (int j = 0; j < 4; ++j)
                acc[f][j] = __builtin_amdgcn_mfma_f32_16x16x32_bf16(
                    avA[f], bvB[j], acc[f][j], 0, 0, 0);
        __builtin_amdgcn_s_setprio(0);

        // ======== X3: vmcnt+beta; MFMA(ks1,mq1); pre-read next tile; stage r3
        if (u + 2 < NT) asm volatile("s_waitcnt vmcnt(7)" ::: "memory");
        else            asm volatile("s_waitcnt vmcnt(0)" ::: "memory");
        asm volatile("s_barrier" ::: "memory");          // beta: bufn ready
        if (u + 1 < NT) {
#pragma unroll
            for (int f = 0; f < 4; ++f)
                avA[f] = *(const bf16x8*)(bufn + aob + f * 1024);
#pragma unroll
            for (int j = 0; j < 4; ++j)
                bvA[j] = *(const bf16x8*)(bufn + bob + j * 1024);
        }
        stage(u + 2, 3, bufc);
        __builtin_amdgcn_s_setprio(1);
#pragma unroll
        for (int f = 0; f < 4; ++f)
#pragma unroll
            for (int j = 0; j < 4; ++j)
                acc[4 + f][j] = __builtin_amdgcn_mfma_f32_16x16x32_bf16(
                    avB[f], bvB[j], acc[4 + f][j], 0, 0, 0);
        __builtin_amdgcn_s_setprio(0);

        if (MIDRELU && u == nt1 - 1) {
#pragma unroll
            for (int j = 0; j < 4; ++j) {
                const float bb = bias1[n0 + wn * 64 + j * 16 + lr];
#pragma unroll
                for (int i = 0; i < 8; ++i)
#pragma unroll
                    for (int r = 0; r < 4; ++r)
                        acc[i][j][r] = fmaxf(acc[i][j][r] + bb, 0.f);
            }
        }
    }

    // ---- epilogue (C/D layout: col=lane&15, row=(lane>>4)*4+reg) ----
    const int cb = n0 + wn * 64 + lr;
    const int rb = m0 + wm * 128 + kq * 4;
#pragma unroll
    for (int j = 0; j < 4; ++j) {
        const int col = cb + j * 16;
        const float bv2 = SPLITK ? 0.f : bias2[col];
#pragma unroll
        for (int i = 0; i < 8; ++i)
#pragma unroll
            for (int r = 0; r < 4; ++r) {
                const int prow = rb + i * 16 + r;
                if (SPLITK) {
                    ((u16*)C)[z * mns + (size_t)prow * ldc + col] = f2b(acc[i][j][r]);
                    continue;
                }
                float v = acc[i][j][r] + bv2;
                if (ENDRELU) v = fmaxf(v, 0.f);
                if (PAIRMUL) {
                    const int ii = ridx[prow * 2 + (col >> 9)];
                    const float g = b2f(fusB[(size_t)((prow >> 9) * O_ + ii) * 1024 + col]);
                    ((u16*)C)[(size_t)prow * ldc + col] = f2b(v * g);
                } else {
                    C[(size_t)prow * ldc + col] = v;
                }
            }
    }
}

// ---------------------------------------------------------------------------
// Split-K bf16 MFMA GEMM (objhid): P[z][M,N] = A*Bt^T over K-slice, f32 out.
// ---------------------------------------------------------------------------
__global__ __launch_bounds__(256, 2)
void gemm_splitk(const u16* __restrict__ A, const u16* __restrict__ Bt,
                 float* __restrict__ P, int K, int KS, int N, int MN)
{
    __shared__ u16 sA[128 * 32];
    __shared__ u16 sB[128 * 32];
    const int tid = threadIdx.x;
    const int w = tid >> 6, l = tid & 63;
    const int m0 = blockIdx.y * 128, n0 = blockIdx.x * 128;
    const int wr = (w >> 1) * 64, wc = (w & 1) * 64;

    const int e0 = w * 512 + l * 8;
    const int r0 = e0 >> 5, c0 = e0 & 31;
    const int r1 = r0 + 64;

    const u16* gA0 = A + (size_t)(m0 + r0) * K + c0;
    const u16* gA1 = A + (size_t)(m0 + r1) * K + c0;
    const u16* gB0 = Bt + (size_t)(n0 + r0) * K + c0;
    const u16* gB1 = Bt + (size_t)(n0 + r1) * K + c0;
    u16* lA0 = sA + w * 512;
    u16* lA1 = sA + 2048 + w * 512;
    u16* lB0 = sB + w * 512;
    u16* lB1 = sB + 2048 + w * 512;

    f32x4 acc[4][4] = {};
    const int lr = l & 15, lk = (l >> 4) * 8;
    const int kbeg = blockIdx.z * KS, kend = kbeg + KS;

    for (int k0 = kbeg; k0 < kend; k0 += 32) {
        __syncthreads();
        GLOAD16(gA0 + k0, lA0);
        GLOAD16(gA1 + k0, lA1);
        GLOAD16(gB0 + k0, lB0);
        GLOAD16(gB1 + k0, lB1);
        __syncthreads();

        bf16x8 av[4], bv[4];
#pragma unroll
        for (int f = 0; f < 4; ++f) {
            av[f] = *(const bf16x8*)&sA[(wr + f * 16 + lr) * 32 + lk];
            bv[f] = *(const bf16x8*)&sB[(wc + f * 16 + lr) * 32 + lk];
        }
#pragma unroll
        for (int i = 0; i < 4; ++i)
#pragma unroll
            for (int j = 0; j < 4; ++j)
                acc[i][j] = __builtin_amdgcn_mfma_f32_16x16x32_bf16(
                    av[i], bv[j], acc[i][j], 0, 0, 0);
    }

    float* out = P + (size_t)blockIdx.z * MN;
    const int cb = n0 + wc + lr;
    const int rb = m0 + wr + (l >> 4) * 4;
#pragma unroll
    for (int j = 0; j < 4; ++j) {
        const int c = cb + j * 16;
#pragma unroll
        for (int i = 0; i < 4; ++i)
#pragma unroll
            for (int r = 0; r < 4; ++r)
                out[(size_t)(rb + i * 16 + r) * N + c] = acc[i][j][r];
    }
}

// reduce NS f32 split-K partials + bias (+relu)
template<int NS, int RELU, int OUTB>
__global__ void k_redux(const float* __restrict__ P, int ldP, int colbase,
                        int logW, size_t MN, const float* __restrict__ bias,
                        void* __restrict__ dst, int ldc)
{
    const int i4 = (blockIdx.x * 256 + threadIdx.x) * 4;
    const int row = i4 >> logW, col = i4 & ((1 << logW) - 1);
    const float* src = P + (size_t)row * ldP + colbase + col;
    float4 s = *(const float4*)src;
#pragma unroll
    for (int z = 1; z < NS; ++z) {
        const float4 v = *(const float4*)(src + (size_t)z * MN);
        s.x += v.x; s.y += v.y; s.z += v.z; s.w += v.w;
    }
    const float4 bb = *(const float4*)(bias + col);
    s.x += bb.x; s.y += bb.y; s.z += bb.z; s.w += bb.w;
    if (RELU) {
        s.x = fmaxf(s.x, 0.f); s.y = fmaxf(s.y, 0.f);
        s.z = fmaxf(s.z, 0.f); s.w = fmaxf(s.w, 0.f);
    }
    if (OUTB) {
        ushort4 o;
        o.x = f2b(s.x); o.y = f2b(s.y); o.z = f2b(s.z); o.w = f2b(s.w);
        *(ushort4*)((u16*)dst + (size_t)row * ldc + col) = o;
    } else {
        *(float4*)((float*)dst + (size_t)row * ldc + col) = s;
    }
}

// fused UA reduce: NS bf16 partials over [1280 x 3072]; grid (3, 1280):
// chunk 0 -> fusedB (bf16, +updim_b); chunks 1,2 -> outAug (f32, +augb, relu).
template<int NS>
__global__ void k_reduxUA(const u16* __restrict__ P, size_t MN,
                          const float* __restrict__ b1, const float* __restrict__ b2,
                          u16* __restrict__ fusedB, float* __restrict__ outAug)
{
    const int row = blockIdx.y;
    const int col = blockIdx.x * 1024 + threadIdx.x * 4;
    const u16* src = P + (size_t)row * 3072 + col;
    float s[4] = {};
#pragma unroll
    for (int z = 0; z < NS; ++z) {
        const ushort4 v = *(const ushort4*)(src + (size_t)z * MN);
        s[0] += b2f(v.x); s[1] += b2f(v.y); s[2] += b2f(v.z); s[3] += b2f(v.w);
    }
    if (col < 1024) {
        const float4 bb = *(const float4*)(b1 + col);
        ushort4 o;
        o.x = f2b(s[0] + bb.x); o.y = f2b(s[1] + bb.y);
        o.z = f2b(s[2] + bb.z); o.w = f2b(s[3] + bb.w);
        *(ushort4*)(fusedB + (size_t)row * 1024 + col) = o;
    } else {
        const int c2 = col - 1024;
        const float4 bb = *(const float4*)(b2 + c2);
        float4 o;
        o.x = fmaxf(s[0] + bb.x, 0.f); o.y = fmaxf(s[1] + bb.y, 0.f);
        o.z = fmaxf(s[2] + bb.z, 0.f); o.w = fmaxf(s[3] + bb.w, 0.f);
        *(float4*)(outAug + (size_t)row * 2048 + c2) = o;
    }
}

// ---------------------------------------------------------------------------
// batched: 6 weight transposes (f32->bf16, 64x64 tiles) + union f32->bf16
// copy, all in ONE launch. Copy blocks are those with blockIdx >= base[6].
// ---------------------------------------------------------------------------
struct TDescs {
    const float* W[6]; u16* T[6];
    int K[6], N[6], nbx[6];
    int base[7];
    const float4* uf; ushort4* ub; int n4; int ncopy;
};

__global__ void k_transpose_all(TDescs d)
{
    const int b = blockIdx.x;
    if (b >= d.base[6]) {
        // union f32 -> bf16 grid-stride copy
        const int cb2 = b - d.base[6];
        int i = cb2 * 256 + threadIdx.x;
        const int stride = d.ncopy * 256;
        for (; i < d.n4; i += stride) {
            float4 v = d.uf[i];
            ushort4 o;
            o.x = f2b(v.x); o.y = f2b(v.y); o.z = f2b(v.z); o.w = f2b(v.w);
            d.ub[i] = o;
        }
        return;
    }
    __shared__ float tile[64][65];
    int i = 0;
    while (b >= d.base[i + 1]) ++i;
    const int loc = b - d.base[i];
    const int nbx = d.nbx[i];
    const int bx = loc % nbx, by = loc / nbx;
    const int K = d.K[i], N = d.N[i];
    const float* W = d.W[i];
    u16* Wt = d.T[i];
    const int k0 = by * 64, n0 = bx * 64;
    const int tr = threadIdx.x >> 6, tc = threadIdx.x & 63;
    for (int rr = tr; rr < 64; rr += 4)
        tile[rr][tc] = W[(size_t)(k0 + rr) * N + n0 + tc];
    __syncthreads();
    for (int rr = tr; rr < 64; rr += 4)
        Wt[(size_t)(n0 + rr) * K + k0 + tc] = f2b(tile[tc][rr]);
}

// fused per-row prep: pack(roi->cat1,aaug; embl->aaug) + softmax@embd + posMLP
__global__ __launch_bounds__(256, 4)
void k_prep(const float* __restrict__ roi, const float* __restrict__ embl,
            const int* __restrict__ labels, const float* __restrict__ logits,
            const float* __restrict__ embd, const float* __restrict__ pos9,
            const float* __restrict__ w1, const float* __restrict__ b1,
            const float* __restrict__ g, const float* __restrict__ bb,
            const float* __restrict__ mu, const float* __restrict__ var,
            const float* __restrict__ w2, const float* __restrict__ b2,
            u16* __restrict__ cat1, u16* __restrict__ aaug)
{
    const int i = blockIdx.x, t = threadIdx.x;   // 256
    __shared__ float red[256];
    __shared__ float pr[NCLS];
    __shared__ float pi[9];
    __shared__ float h[32];
    u16* c1 = cat1 + (size_t)i * 4992;
    u16* aa = aaug + (size_t)i * 5376;

    // ---- softmax(logits[i]) -> pr ----
    float v = (t < NCLS) ? logits[i * NCLS + t] : -3.4e38f;
    red[t] = v; __syncthreads();
    for (int s = 128; s > 0; s >>= 1) {
        if (t < s) red[t] = fmaxf(red[t], red[t + s]);
        __syncthreads();
    }
    const float mx = red[0]; __syncthreads();
    float e = (t < NCLS) ? expf(v - mx) : 0.f;
    red[t] = e; __syncthreads();
    for (int s = 128; s > 0; s >>= 1) {
        if (t < s) red[t] += red[t + s];
        __syncthreads();
    }
    const float inv = 1.f / red[0];
    if (t < NCLS) pr[t] = e * inv;
    // ---- pos fc1 + BN (threads 0-31) ----
    if (t < 9) pi[t] = pos9[i * 9 + t];
    __syncthreads();
    if (t < 32) {
        float s = b1[t];
        for (int k = 0; k < 9; ++k) s += pi[k] * w1[k * 32 + t];
        h[t] = (s - mu[t]) * rsqrtf(var[t] + 1e-5f) * g[t] + bb[t];
    }
    __syncthreads();

    // ---- pack roi + emb_label ----
    const float* r = roi + (size_t)i * INCH;
    for (int c = t; c < INCH; c += 256) {
        u16 bv = f2b(r[c]);
        c1[c] = bv;
        aa[EMB_ + c] = bv;
    }
    const float* el = embl + (size_t)labels[i] * EMB_;
    for (int c = t; c < EMB_; c += 256) aa[c] = f2b(el[c]);

    // ---- pr @ embd -> cat1[4096:4864] ----
    for (int j = t; j < EMB_; j += 256) {
        float s = 0.f;
        for (int k = 0; k < NCLS; ++k) s += pr[k] * embd[k * EMB_ + j];
        c1[INCH + j] = f2b(s);
    }
    // ---- pos fc2 + relu -> cat1[4864:4992] ----
    if (t < GEO_) {
        float s = b2[t];
        for (int k = 0; k < 32; ++k) s += h[k] * w2[k * GEO_ + t];
        c1[INCH + EMB_ + t] = f2b(fmaxf(s, 0.f));
    }
}

// geo(32) + spt1 (K=32) + relu, 16 pairs/block, w1 staged in LDS.
__global__ __launch_bounds__(256, 2)
void k_geo_spt1(const float* __restrict__ boxes, const int* __restrict__ ridx,
                const float* __restrict__ w1, const float* __restrict__ b1,
                u16* __restrict__ out)
{
    __shared__ float w1s[32][512];
    __shared__ float geos[16][32];
    const int t = threadIdx.x;       // 256
    const int p0 = blockIdx.x * 16;
    for (int i = t; i < 32 * 512; i += 256)
        w1s[i >> 9][i & 511] = w1[i];
    if (t < 16) {
        const int p = p0 + t;
        const int b = p >> 9;
        const int i0 = ridx[p * 2 + 0];
        const int i1 = ridx[p * 2 + 1];
        const float* x = boxes + (size_t)(b * O_ + i0) * 4;
        const float* y = boxes + (size_t)(b * O_ + i1) * 4;
        float a0 = x[0], a1 = x[1], a2 = x[2], a3 = x[3];
        float c0 = y[0], c1 = y[1], c2 = y[2], c3 = y[3];
        float* g = geos[t];
        g[0] = a0; g[1] = a1; g[2] = a2; g[3] = a3;
        g[4] = (a0 + a2) * 0.5f; g[5] = (a1 + a3) * 0.5f;
        g[6] = a2 - a0; g[7] = a3 - a1;
        g[8] = c0; g[9] = c1; g[10] = c2; g[11] = c3;
        g[12] = (c0 + c2) * 0.5f; g[13] = (c1 + c3) * 0.5f;
        g[14] = c2 - c0; g[15] = c3 - c1;
        float u0 = fminf(a0, c0), u1 = fminf(a1, c1);
        float u2 = fmaxf(a2, c2), u3 = fmaxf(a3, c3);
        g[16] = u0; g[17] = u1; g[18] = u2; g[19] = u3;
        g[20] = (u0 + u2) * 0.5f; g[21] = (u1 + u3) * 0.5f;
        g[22] = u2 - u0; g[23] = u3 - u1;
        float q0 = fmaxf(a0, c0), q1 = fmaxf(a1, c1);
        float q2 = fminf(a2, c2), q3 = fminf(a3, c3);
        if (q0 <= q2 && q1 <= q3) {
            g[24] = q0; g[25] = q1; g[26] = q2; g[27] = q3;
            g[28] = (q0 + q2) * 0.5f; g[29] = (q1 + q3) * 0.5f;
            g[30] = q2 - q0; g[31] = q3 - q1;
        } else {
            for (int k = 24; k < 32; ++k) g[k] = 0.f;
        }
    }
    __syncthreads();
    for (int e = t; e < 16 * 512; e += 256) {
        const int p = e >> 9, j = e & 511;
        float s = b1[j];
#pragma unroll
        for (int k = 0; k < 32; ++k) s += geos[p][k] * w1s[k][j];
        out[(size_t)(p0 + p) * HID_ + j] = f2b(fmaxf(s, 0.f));
    }
}

// ---------------------------------------------------------------------------
extern "C" void kernel_launch(void* const* d_in, const int* in_sizes, int n_in,
                              void* d_out, int out_size, void* d_ws, size_t ws_size,
                              hipStream_t stream)
{
    (void)in_sizes; (void)n_in; (void)out_size; (void)ws_size;
    const float* roi     = (const float*)d_in[0];
    const float* unionf  = (const float*)d_in[1];
    const float* logits  = (const float*)d_in[2];
    const float* pos9    = (const float*)d_in[3];
    const float* boxes   = (const float*)d_in[4];
    const int*   labels  = (const int*)d_in[5];
    const int*   relidx  = (const int*)d_in[6];
    const float* embd    = (const float*)d_in[7];
    const float* embl    = (const float*)d_in[8];
    const float* relup_w = (const float*)d_in[9];
    const float* relup_b = (const float*)d_in[10];
    const float* updim_w = (const float*)d_in[11];
    const float* updim_b = (const float*)d_in[12];
    const float* fc1w    = (const float*)d_in[13];
    const float* fc1b    = (const float*)d_in[14];
    const float* bng     = (const float*)d_in[15];
    const float* bnb     = (const float*)d_in[16];
    const float* bnm     = (const float*)d_in[17];
    const float* bnv     = (const float*)d_in[18];
    const float* fc2w    = (const float*)d_in[19];
    const float* fc2b    = (const float*)d_in[20];
    const float* spt1w   = (const float*)d_in[21];
    const float* spt1b   = (const float*)d_in[22];
    const float* spt2w   = (const float*)d_in[23];
    const float* spt2b   = (const float*)d_in[24];
    const float* finw    = (const float*)d_in[25];
    const float* finb    = (const float*)d_in[26];
    const float* objhw   = (const float*)d_in[27];
    const float* objhb   = (const float*)d_in[28];
    const float* augw    = (const float*)d_in[29];
    const float* augb    = (const float*)d_in[30];

    char* wp = (char*)d_ws;
    auto take = [&](size_t bytes) {
        char* r = wp; wp += (bytes + 255) & ~(size_t)255; return r;
    };
    u16* wtObj   = (u16*)take((size_t)512  * 4992 * 2);
    u16* wtUA    = (u16*)take((size_t)3072 * 5376 * 2);   // updim rows 0-1023, aug 1024-3071
    u16* wtSpt2  = (u16*)take((size_t)1024 * 512  * 2);
    u16* wtFin   = (u16*)take((size_t)2048 * 1024 * 2);
    u16* wtRelup = (u16*)take((size_t)2048 * 4096 * 2);
    u16* aCat1   = (u16*)take((size_t)1280 * 4992 * 2);
    u16* aAug    = (u16*)take((size_t)1280 * 5376 * 2);
    u16* aUnion  = (u16*)take((size_t)8192 * 4096 * 2);
    u16* aSpt1   = (u16*)take((size_t)8192 * 512  * 2);
    u16* fusedB  = (u16*)take((size_t)1280 * 1024 * 2);
    u16* aPair   = (u16*)take((size_t)8192 * 1024 * 2);
    float* Pscr  = (float*)take((size_t)8192 * 1024 * 4); // scratch after aPair
    (void)Pscr;
    // partial buffer aliases (aPair + Pscr) = 50.3MB:
    //   objhid: 6 x 1280x512 f32   = 15.7MB
    //   UA:     4 x 1280x3072 bf16 = 31.5MB
    // both dead before spt2's PAIRMUL epilogue writes aPair.
    float* Pbuf  = (float*)aPair;
    u16*   PbufB = (u16*)aPair;

    float* outAug = (float*)d_out;                          // [1280,2048]
    float* outRel = (float*)d_out + (size_t)1280 * 2048;    // [8192,2048]

    // all 6 weight transposes + union f32->bf16 in one launch
    TDescs td;
    td.W[0] = objhw;   td.T[0] = wtObj;                      td.K[0] = 4992; td.N[0] = 512;
    td.W[1] = updim_w; td.T[1] = wtUA;                       td.K[1] = 5376; td.N[1] = 1024;
    td.W[2] = augw;    td.T[2] = wtUA + (size_t)1024 * 5376; td.K[2] = 5376; td.N[2] = 2048;
    td.W[3] = spt2w;   td.T[3] = wtSpt2;                     td.K[3] = 512;  td.N[3] = 1024;
    td.W[4] = finw;    td.T[4] = wtFin;                      td.K[4] = 1024; td.N[4] = 2048;
    td.W[5] = relup_w; td.T[5] = wtRelup;                    td.K[5] = 4096; td.N[5] = 2048;
    int tb = 0;
    for (int i = 0; i < 6; ++i) {
        td.nbx[i] = td.N[i] / 64;
        td.base[i] = tb;
        tb += (td.N[i] / 64) * (td.K[i] / 64);
    }
    td.base[6] = tb;   // 7344
    td.uf = (const float4*)unionf;
    td.ub = (ushort4*)aUnion;
    td.n4 = (8192 * 4096) / 4;
    td.ncopy = 2048;
    k_transpose_all<<<tb + 2048, 256, 0, stream>>>(td);

    // activations prep
    k_prep<<<1280, 256, 0, stream>>>(roi, embl, labels, logits, embd, pos9,
                                     fc1w, fc1b, bng, bnb, bnm, bnv, fc2w, fc2b,
                                     aCat1, aAug);
    k_geo_spt1<<<512, 256, 0, stream>>>(boxes, relidx, spt1w, spt1b, aSpt1);

    // aug_hid = cat1 @ objhid  (split-K 6 f32 -> bf16 cols of aAug)
    gemm_splitk<<<dim3(4, 10, 6), 256, 0, stream>>>(aCat1, wtObj, Pbuf, 4992, 832,
                                                    512, 1280 * 512);
    k_redux<6, 0, 1><<<640, 256, 0, stream>>>(Pbuf, 512, 0, 9, (size_t)1280 * 512,
                                              objhb, (void*)(aAug + 4864), 5376);

    // [fused | augment_pre] = aAug @ [updim | aug]  via gemm256 split-K
    // (S=4, grid 60x4=240, K-slice 1344 = 21 tiles of 64, bf16 partials)
    gemm256<0, 0, 0, 1><<<dim3(240), 512, 0, stream>>>(
        aAug, 5376, wtUA, 5376, 21,
        aAug, 5376, wtUA, 5376, 0,
        updim_b, updim_b, (float*)PbufB, 3072, 12, nullptr, nullptr,
        60, (size_t)1280 * 3072);
    k_reduxUA<4><<<dim3(3, 1280), 256, 0, stream>>>(PbufB, (size_t)1280 * 3072,
                                                    updim_b, augb, fusedB, outAug);

    // spt = relu(spt1out @ spt2 + b); epilogue: aPair = bf16(spt * gather(fused))
    gemm256<0, 1, 1, 0><<<dim3(128), 512, 0, stream>>>(
        aSpt1, 512, wtSpt2, 512, 8,
        aSpt1, 512, wtSpt2, 512, 0,
        spt2b, spt2b, (float*)aPair, 1024, 4, relidx, fusedB, 0, 0);

    // rel_features = relu(pair@fin + finb) + union@relup + relup_b  (fused)
    gemm256<1, 0, 0, 0><<<dim3(256), 512, 0, stream>>>(
        aPair, 1024, wtFin, 1024, 16,
        aUnion, 4096, wtRelup, 4096, 64,
        finb, relup_b, outRel, 2048, 8, nullptr, nullptr, 0, 0);
}